// Round 2
// baseline (201.985 us; speedup 1.0000x reference)
//
#include <hip/hip_runtime.h>

// ---------------------------------------------------------------------------
// LocalCausalSelfAttention: x@Wqkv+b -> RoPE(q,k) -> windowed causal attn
// -> @Wproj+b.  B=2 T=2048 C=1024 H=16 Dh=64 W=128.
// External I/O: fp32 (per reference). Internal: bf16 MFMA compute.
// ---------------------------------------------------------------------------

using bf16x8 = short  __attribute__((ext_vector_type(8)));
using f32x4  = float __attribute__((ext_vector_type(4)));

__device__ __forceinline__ float bf2f(unsigned short u) {
    return __uint_as_float(((unsigned int)u) << 16);
}
__device__ __forceinline__ unsigned short f2bf(float f) {
    unsigned int u = __float_as_uint(f);
    u += 0x7fffu + ((u >> 16) & 1u);      // RNE
    return (unsigned short)(u >> 16);
}

// ---------------- fp32 -> bf16 elementwise (vectorized) ---------------------
__global__ __launch_bounds__(256) void f32_to_bf16_kernel(
        const float* __restrict__ in, unsigned short* __restrict__ out, int n4) {
    int i = blockIdx.x * 256 + threadIdx.x;
    int stride = gridDim.x * 256;
    for (; i < n4; i += stride) {
        float4 v = ((const float4*)in)[i];
        ushort4 o;
        o.x = f2bf(v.x); o.y = f2bf(v.y); o.z = f2bf(v.z); o.w = f2bf(v.w);
        ((ushort4*)out)[i] = o;
    }
}

// ---------------- transpose + downcast (fp32 KxN -> bf16 NxK) ---------------
__global__ __launch_bounds__(256) void transpose_f32_bf16(
        const float* __restrict__ W, unsigned short* __restrict__ WT,
        int rows, int cols) {
    __shared__ unsigned short tile[32][33];
    int c0 = blockIdx.x * 32, r0 = blockIdx.y * 32;
    int tx = threadIdx.x, ty = threadIdx.y;
    for (int i = ty; i < 32; i += 8)
        tile[i][tx] = f2bf(W[(size_t)(r0 + i) * cols + c0 + tx]);
    __syncthreads();
    for (int i = ty; i < 32; i += 8)
        WT[(size_t)(c0 + i) * rows + r0 + tx] = tile[tx][i];
}

// ---------------- GEMM: C[M,N] = A[M,K] @ Bt[N,K]^T + bias ------------------
// A,Bt bf16; bias fp32; C bf16 or fp32. 128x128 tile, BK=32, 4 waves (2x2),
// wave tile 64x64 = 4x4 frags of 16x16x32 MFMA.
#define GBM 128
#define GBN 128
#define GBK 32
#define GLD 40   // LDS row stride (32 + 8 pad)

template <bool OUT_BF16>
__global__ __launch_bounds__(256) void gemm_bt(
        const unsigned short* __restrict__ A,
        const unsigned short* __restrict__ Bt,
        const float* __restrict__ bias,
        void* __restrict__ Cv,
        int M, int N, int K) {
    __shared__ unsigned short As[GBM * GLD];
    __shared__ unsigned short Bs[GBN * GLD];
    int row0 = blockIdx.y * GBM, col0 = blockIdx.x * GBN;
    int tid = threadIdx.x;
    int lane = tid & 63, wid = tid >> 6;
    int wr = wid >> 1, wc = wid & 1;
    int fr = lane & 15, kg = (lane >> 4) * 8;

    f32x4 acc[4][4];
    #pragma unroll
    for (int i = 0; i < 4; ++i)
        #pragma unroll
        for (int j = 0; j < 4; ++j)
            acc[i][j] = (f32x4){0.f, 0.f, 0.f, 0.f};

    for (int kt = 0; kt < K; kt += GBK) {
        __syncthreads();
        #pragma unroll
        for (int p = 0; p < 2; ++p) {             // 512 chunks of 8 els
            int chunk = tid + p * 256;
            int r = chunk >> 2;
            int c = (chunk & 3) << 3;
            *(bf16x8*)&As[r * GLD + c] =
                *(const bf16x8*)(A + (size_t)(row0 + r) * K + kt + c);
            *(bf16x8*)&Bs[r * GLD + c] =
                *(const bf16x8*)(Bt + (size_t)(col0 + r) * K + kt + c);
        }
        __syncthreads();
        bf16x8 af[4], bfv[4];
        #pragma unroll
        for (int i = 0; i < 4; ++i) {
            af[i]  = *(const bf16x8*)&As[(wr * 64 + i * 16 + fr) * GLD + kg];
            bfv[i] = *(const bf16x8*)&Bs[(wc * 64 + i * 16 + fr) * GLD + kg];
        }
        #pragma unroll
        for (int i = 0; i < 4; ++i)
            #pragma unroll
            for (int j = 0; j < 4; ++j)
                acc[i][j] = __builtin_amdgcn_mfma_f32_16x16x32_bf16(
                                af[i], bfv[j], acc[i][j], 0, 0, 0);
    }

    int rg = (lane >> 4) * 4;
    #pragma unroll
    for (int j = 0; j < 4; ++j) {
        int col = col0 + wc * 64 + j * 16 + fr;
        float bz = bias[col];
        #pragma unroll
        for (int i = 0; i < 4; ++i) {
            #pragma unroll
            for (int r = 0; r < 4; ++r) {
                int row = row0 + wr * 64 + i * 16 + rg + r;
                float val = acc[i][j][r] + bz;
                if constexpr (OUT_BF16)
                    ((unsigned short*)Cv)[(size_t)row * N + col] = f2bf(val);
                else
                    ((float*)Cv)[(size_t)row * N + col] = val;
            }
        }
    }
}

// ---------------- RoPE table: tab[t*32+i] = {cos,sin}(t * 10000^{-i/32}) ----
__global__ __launch_bounds__(256) void rope_table_kernel(float* __restrict__ tab) {
    int idx = blockIdx.x * 256 + threadIdx.x;   // 65536 = 2048*32
    int t = idx >> 5, i = idx & 31;
    float inv = powf(10000.0f, -(float)i / 32.0f);
    float ang = (float)t * inv;
    tab[idx * 2]     = cosf(ang);
    tab[idx * 2 + 1] = sinf(ang);
}

// ---------------- RoPE apply (in-place on bf16 q,k halves of qkv) -----------
__global__ __launch_bounds__(256) void rope_apply_kernel(
        unsigned short* __restrict__ qkv, const float* __restrict__ tab) {
    int idx = blockIdx.x * 256 + threadIdx.x;   // B*T*1024 pairs = 4194304
    int p = idx & 1023; int row = idx >> 10;
    int t = row & 2047;                          // row = b*2048 + t
    int sel = p >> 9;                            // 0=q, 1=k
    int hp = p & 511; int h = hp >> 5; int i = hp & 31;
    int col = sel * 1024 + h * 64 + 2 * i;
    unsigned int* addr = (unsigned int*)(qkv + (size_t)row * 3072 + col);
    unsigned int u = *addr;
    float x0 = __uint_as_float(u << 16);
    float x1 = __uint_as_float(u & 0xffff0000u);
    float c = tab[(t * 32 + i) * 2];
    float s = tab[(t * 32 + i) * 2 + 1];
    float y0 = x0 * c - x1 * s;
    float y1 = x1 * c + x0 * s;
    *addr = (unsigned int)f2bf(y0) | ((unsigned int)f2bf(y1) << 16);
}

// ---------------- windowed causal attention (bf16 in/out) -------------------
// Block: 256 thr = 4 waves, (b, h, 32-query tile). Wave owns 8 queries.
#define ALD 66    // K/V/Q LDS stride: 33 words (odd) -> conflict-free
#define AKM 160   // max staged keys (nk <= 159)

__global__ __launch_bounds__(256) void attn_kernel(
        const unsigned short* __restrict__ qkv, unsigned short* __restrict__ aout) {
    __shared__ unsigned short Ks[AKM * ALD];
    __shared__ unsigned short Vs[AKM * ALD];
    __shared__ unsigned short Qs[32 * ALD];
    __shared__ unsigned short Ps[32 * AKM];

    int bid = blockIdx.x;
    int b = bid >> 10;
    int h = (bid >> 6) & 15;
    int Q0 = (bid & 63) * 32;
    int kbase = Q0 - 127; if (kbase < 0) kbase = 0;
    int nk = Q0 + 32 - kbase;                    // <= 159
    int tid = threadIdx.x;

    {
        int c = (tid & 7) * 8;
        for (int r = tid >> 3; r < nk; r += 32) {
            const unsigned short* g =
                qkv + (size_t)(b * 2048 + kbase + r) * 3072 + 1024 + h * 64 + c;
            uint4 kv = *(const uint4*)g;
            uint4 vv = *(const uint4*)(g + 1024);
            unsigned int* dk = (unsigned int*)&Ks[r * ALD + c];
            dk[0] = kv.x; dk[1] = kv.y; dk[2] = kv.z; dk[3] = kv.w;
            unsigned int* dv = (unsigned int*)&Vs[r * ALD + c];
            dv[0] = vv.x; dv[1] = vv.y; dv[2] = vv.z; dv[3] = vv.w;
        }
        int r = tid >> 3;
        const unsigned short* g =
            qkv + (size_t)(b * 2048 + Q0 + r) * 3072 + h * 64 + c;
        uint4 qv = *(const uint4*)g;
        unsigned int* dq = (unsigned int*)&Qs[r * ALD + c];
        dq[0] = qv.x; dq[1] = qv.y; dq[2] = qv.z; dq[3] = qv.w;
    }
    __syncthreads();

    int lane = tid & 63, w = tid >> 6;
    int qw0 = Q0 + 8 * w;
    int kw0rel = qw0 - 127 - kbase;

    // ---- phase 1: scores ----
    float S[8][3];
    #pragma unroll
    for (int qi = 0; qi < 8; ++qi)
        #pragma unroll
        for (int ki = 0; ki < 3; ++ki) S[qi][ki] = 0.f;

    int kr_[3]; bool kval[3];
    const unsigned short* kp[3];
    #pragma unroll
    for (int ki = 0; ki < 3; ++ki) {
        int kr = kw0rel + lane + 64 * ki;
        kr_[ki] = kr;
        kval[ki] = (kr >= 0) && (kr < nk);
        int kc = kr < 0 ? 0 : (kr >= nk ? nk - 1 : kr);
        kp[ki] = &Ks[kc * ALD];
    }
    const unsigned short* qp = &Qs[w * 8 * ALD];

    #pragma unroll 4
    for (int dp = 0; dp < 32; ++dp) {
        unsigned int u0 = *(const unsigned int*)(kp[0] + 2 * dp);
        unsigned int u1 = *(const unsigned int*)(kp[1] + 2 * dp);
        unsigned int u2 = *(const unsigned int*)(kp[2] + 2 * dp);
        float k0a = __uint_as_float(u0 << 16), k0b = __uint_as_float(u0 & 0xffff0000u);
        float k1a = __uint_as_float(u1 << 16), k1b = __uint_as_float(u1 & 0xffff0000u);
        float k2a = __uint_as_float(u2 << 16), k2b = __uint_as_float(u2 & 0xffff0000u);
        #pragma unroll
        for (int qi = 0; qi < 8; ++qi) {
            unsigned int qu = *(const unsigned int*)(qp + qi * ALD + 2 * dp);
            float qa = __uint_as_float(qu << 16), qb = __uint_as_float(qu & 0xffff0000u);
            S[qi][0] += qa * k0a + qb * k0b;
            S[qi][1] += qa * k1a + qb * k1b;
            S[qi][2] += qa * k2a + qb * k2b;
        }
    }

    // ---- phase 2: mask + softmax (normalized) -> Ps ----
    const float scale = 0.125f;                  // 1/sqrt(64)
    #pragma unroll
    for (int qi = 0; qi < 8; ++qi) {
        float sv[3]; float m = -1e30f;
        #pragma unroll
        for (int ki = 0; ki < 3; ++ki) {
            int off = lane + 64 * ki;            // window <=> off in [qi, qi+127]
            bool ok = kval[ki] && (off >= qi) && (off <= qi + 127);
            sv[ki] = ok ? S[qi][ki] * scale : -1e30f;
            m = fmaxf(m, sv[ki]);
        }
        #pragma unroll
        for (int o = 1; o < 64; o <<= 1) m = fmaxf(m, __shfl_xor(m, o));
        float p[3]; float ls = 0.f;
        #pragma unroll
        for (int ki = 0; ki < 3; ++ki) { p[ki] = __expf(sv[ki] - m); ls += p[ki]; }
        #pragma unroll
        for (int o = 1; o < 64; o <<= 1) ls += __shfl_xor(ls, o);
        float rinv = 1.0f / ls;
        #pragma unroll
        for (int ki = 0; ki < 3; ++ki) {
            int kr = kr_[ki];
            if (kr >= 0 && kr < nk)
                Ps[(w * 8 + qi) * AKM + kr] = f2bf(p[ki] * rinv);
        }
    }

    // ---- phase 3: O = P.V (lane = dim) ----
    float O[8];
    #pragma unroll
    for (int qi = 0; qi < 8; ++qi) O[qi] = 0.f;
    int kstart = kw0rel > 0 ? kw0rel : 0;
    int kend = kw0rel + 135; if (kend > nk) kend = nk;
    int j = kstart;
    if (j < kend && (j & 1)) {
        float v = bf2f(Vs[j * ALD + lane]);
        #pragma unroll
        for (int qi = 0; qi < 8; ++qi)
            O[qi] += bf2f(Ps[(w * 8 + qi) * AKM + j]) * v;
        ++j;
    }
    for (; j + 1 < kend; j += 2) {
        float v0 = bf2f(Vs[j * ALD + lane]);
        float v1 = bf2f(Vs[(j + 1) * ALD + lane]);
        const unsigned short* pr = &Ps[w * 8 * AKM + j];
        #pragma unroll
        for (int qi = 0; qi < 8; ++qi) {
            unsigned int pu = *(const unsigned int*)(pr + qi * AKM);
            O[qi] += __uint_as_float(pu << 16) * v0
                   + __uint_as_float(pu & 0xffff0000u) * v1;
        }
    }
    if (j < kend) {
        float v = bf2f(Vs[j * ALD + lane]);
        #pragma unroll
        for (int qi = 0; qi < 8; ++qi)
            O[qi] += bf2f(Ps[(w * 8 + qi) * AKM + j]) * v;
    }
    #pragma unroll
    for (int qi = 0; qi < 8; ++qi) {
        int t = qw0 + qi;
        aout[(size_t)(b * 2048 + t) * 1024 + h * 64 + lane] = f2bf(O[qi]);
    }
}

// ---------------------------------------------------------------------------
extern "C" void kernel_launch(void* const* d_in, const int* in_sizes, int n_in,
                              void* d_out, int out_size, void* d_ws, size_t ws_size,
                              hipStream_t stream) {
    const float* x     = (const float*)d_in[0];  // [2,2048,1024] fp32
    const float* Wqkv  = (const float*)d_in[1];  // [1024,3072]  fp32
    const float* bqkv  = (const float*)d_in[2];  // [3072]       fp32
    const float* Wproj = (const float*)d_in[3];  // [1024,1024]  fp32
    const float* bproj = (const float*)d_in[4];  // [1024]       fp32
    float* out = (float*)d_out;                  // [2,2048,1024] fp32

    char* ws = (char*)d_ws;
    unsigned short* WqkvT  = (unsigned short*)(ws);                // bf16 3072x1024:  6291456 B
    unsigned short* WprojT = (unsigned short*)(ws + 6291456);      // bf16 1024x1024:  2097152 B
    unsigned short* xb     = (unsigned short*)(ws + 8388608);      // bf16 4096x1024:  8388608 B
    unsigned short* qkv    = (unsigned short*)(ws + 16777216);     // bf16 4096x3072: 25165824 B
    float*          tab    = (float*)        (ws + 41943040);      // f32 2048x32x2:    524288 B
    unsigned short* attno  = (unsigned short*)(ws + 42467328);     // bf16 4096x1024:  8388608 B
                                                                   // total: 50855936 B

    transpose_f32_bf16<<<dim3(96, 32), dim3(32, 8), 0, stream>>>(Wqkv,  WqkvT,  1024, 3072);
    transpose_f32_bf16<<<dim3(32, 32), dim3(32, 8), 0, stream>>>(Wproj, WprojT, 1024, 1024);
    f32_to_bf16_kernel<<<1024, 256, 0, stream>>>(x, xb, 4194304 / 4);
    rope_table_kernel<<<256, 256, 0, stream>>>(tab);

    // qkv = xb @ WqkvT^T + bqkv   (bf16 out)
    gemm_bt<true><<<dim3(24, 32), 256, 0, stream>>>(xb, WqkvT, bqkv, qkv, 4096, 3072, 1024);
    // RoPE in place on q,k
    rope_apply_kernel<<<16384, 256, 0, stream>>>(qkv, tab);
    // windowed causal attention
    attn_kernel<<<2048, 256, 0, stream>>>(qkv, attno);
    // out = attno @ WprojT^T + bproj   (fp32 out)
    gemm_bt<false><<<dim3(8, 32), 256, 0, stream>>>(attno, WprojT, bproj, out, 4096, 1024, 1024);
}

// Round 4
// 122.363 us; speedup vs baseline: 1.6507x; 1.6507x over previous
//
#include <hip/hip_runtime.h>

// ---------------------------------------------------------------------------
// LocalCausalSelfAttention: x@Wqkv+b -> RoPE(q,k) -> windowed causal attn
// -> @Wproj+b.  B=2 T=2048 C=1024 H=16 Dh=64 W=128.
// External I/O: fp32. Internal: bf16 MFMA compute.
// ---------------------------------------------------------------------------

using bf16x8 = short  __attribute__((ext_vector_type(8)));
using f32x4  = float __attribute__((ext_vector_type(4)));

__device__ __forceinline__ float bf2f(unsigned short u) {
    return __uint_as_float(((unsigned int)u) << 16);
}
__device__ __forceinline__ unsigned short f2bf(float f) {
    unsigned int u = __float_as_uint(f);
    u += 0x7fffu + ((u >> 16) & 1u);      // RNE
    return (unsigned short)(u >> 16);
}

// ---------------- fp32 -> bf16 elementwise (vectorized) ---------------------
__global__ __launch_bounds__(256) void f32_to_bf16_kernel(
        const float* __restrict__ in, unsigned short* __restrict__ out, int n4) {
    int i = blockIdx.x * 256 + threadIdx.x;
    int stride = gridDim.x * 256;
    for (; i < n4; i += stride) {
        float4 v = ((const float4*)in)[i];
        ushort4 o;
        o.x = f2bf(v.x); o.y = f2bf(v.y); o.z = f2bf(v.z); o.w = f2bf(v.w);
        ((ushort4*)out)[i] = o;
    }
}

// ---------------- transpose + downcast (fp32 KxN -> bf16 NxK) ---------------
__global__ __launch_bounds__(256) void transpose_f32_bf16(
        const float* __restrict__ W, unsigned short* __restrict__ WT,
        int rows, int cols) {
    __shared__ unsigned short tile[32][33];
    int c0 = blockIdx.x * 32, r0 = blockIdx.y * 32;
    int tx = threadIdx.x, ty = threadIdx.y;
    for (int i = ty; i < 32; i += 8)
        tile[i][tx] = f2bf(W[(size_t)(r0 + i) * cols + c0 + tx]);
    __syncthreads();
    for (int i = ty; i < 32; i += 8)
        WT[(size_t)(c0 + i) * rows + r0 + tx] = tile[tx][i];
}

// ---------------- GEMM: C[M,N] = A[M,K] @ Bt[N,K]^T + bias ------------------
#define GBM 128
#define GBN 128
#define GBK 32
#define GLD 40   // LDS row stride (32 + 8 pad)

template <bool OUT_BF16>
__global__ __launch_bounds__(256) void gemm_bt(
        const unsigned short* __restrict__ A,
        const unsigned short* __restrict__ Bt,
        const float* __restrict__ bias,
        void* __restrict__ Cv,
        int M, int N, int K) {
    __shared__ unsigned short As[GBM * GLD];
    __shared__ unsigned short Bs[GBN * GLD];
    int row0 = blockIdx.y * GBM, col0 = blockIdx.x * GBN;
    int tid = threadIdx.x;
    int lane = tid & 63, wid = tid >> 6;
    int wr = wid >> 1, wc = wid & 1;
    int fr = lane & 15, kg = (lane >> 4) * 8;

    f32x4 acc[4][4];
    #pragma unroll
    for (int i = 0; i < 4; ++i)
        #pragma unroll
        for (int j = 0; j < 4; ++j)
            acc[i][j] = (f32x4){0.f, 0.f, 0.f, 0.f};

    for (int kt = 0; kt < K; kt += GBK) {
        __syncthreads();
        #pragma unroll
        for (int p = 0; p < 2; ++p) {
            int chunk = tid + p * 256;
            int r = chunk >> 2;
            int c = (chunk & 3) << 3;
            *(bf16x8*)&As[r * GLD + c] =
                *(const bf16x8*)(A + (size_t)(row0 + r) * K + kt + c);
            *(bf16x8*)&Bs[r * GLD + c] =
                *(const bf16x8*)(Bt + (size_t)(col0 + r) * K + kt + c);
        }
        __syncthreads();
        bf16x8 af[4], bfv[4];
        #pragma unroll
        for (int i = 0; i < 4; ++i) {
            af[i]  = *(const bf16x8*)&As[(wr * 64 + i * 16 + fr) * GLD + kg];
            bfv[i] = *(const bf16x8*)&Bs[(wc * 64 + i * 16 + fr) * GLD + kg];
        }
        #pragma unroll
        for (int i = 0; i < 4; ++i)
            #pragma unroll
            for (int j = 0; j < 4; ++j)
                acc[i][j] = __builtin_amdgcn_mfma_f32_16x16x32_bf16(
                                af[i], bfv[j], acc[i][j], 0, 0, 0);
    }

    int rg = (lane >> 4) * 4;
    #pragma unroll
    for (int j = 0; j < 4; ++j) {
        int col = col0 + wc * 64 + j * 16 + fr;
        float bz = bias[col];
        #pragma unroll
        for (int i = 0; i < 4; ++i) {
            #pragma unroll
            for (int r = 0; r < 4; ++r) {
                int row = row0 + wr * 64 + i * 16 + rg + r;
                float val = acc[i][j][r] + bz;
                if constexpr (OUT_BF16)
                    ((unsigned short*)Cv)[(size_t)row * N + col] = f2bf(val);
                else
                    ((float*)Cv)[(size_t)row * N + col] = val;
            }
        }
    }
}

// ---------------- RoPE table ------------------------------------------------
__global__ __launch_bounds__(256) void rope_table_kernel(float* __restrict__ tab) {
    int idx = blockIdx.x * 256 + threadIdx.x;   // 65536 = 2048*32
    int t = idx >> 5, i = idx & 31;
    float inv = powf(10000.0f, -(float)i / 32.0f);
    float ang = (float)t * inv;
    tab[idx * 2]     = cosf(ang);
    tab[idx * 2 + 1] = sinf(ang);
}

// ---------------- RoPE apply (in-place on bf16 q,k halves of qkv) -----------
__global__ __launch_bounds__(256) void rope_apply_kernel(
        unsigned short* __restrict__ qkv, const float* __restrict__ tab) {
    int idx = blockIdx.x * 256 + threadIdx.x;   // 4194304 pairs
    int p = idx & 1023; int row = idx >> 10;
    int t = row & 2047;
    int sel = p >> 9;
    int hp = p & 511; int h = hp >> 5; int i = hp & 31;
    int col = sel * 1024 + h * 64 + 2 * i;
    unsigned int* addr = (unsigned int*)(qkv + (size_t)row * 3072 + col);
    unsigned int u = *addr;
    float x0 = __uint_as_float(u << 16);
    float x1 = __uint_as_float(u & 0xffff0000u);
    float c = tab[(t * 32 + i) * 2];
    float s = tab[(t * 32 + i) * 2 + 1];
    float y0 = x0 * c - x1 * s;
    float y1 = x1 * c + x0 * s;
    *addr = (unsigned int)f2bf(y0) | ((unsigned int)f2bf(y1) << 16);
}

// ---------------- MFMA windowed causal attention ----------------------------
// Block = (b, h, 64-query tile), 4 waves, wave owns 16 queries.
// QK^T: Q,K frags direct from global (row-contiguous 16B/lane, L1/L2-hot).
// Softmax in-register on D-layout (4 rows/lane), 16-lane shfl reduce.
// PV: P->LDS bf16 (stride 168), V staged transposed Vt[64][200].
#define VTS 200   // Vt col stride (keys): mult of 8 (16B align), 2-way banks
#define PSS 168   // P row stride: mult of 8, 2-way banks, >= 160

__global__ __launch_bounds__(256) void attn_kernel(
        const unsigned short* __restrict__ qkv, unsigned short* __restrict__ aout) {
    __shared__ unsigned short Vt[64 * VTS];        // 25600 B
    __shared__ unsigned short Ps[4 * 16 * PSS];    // 21504 B

    int bid = blockIdx.x;
    int h  = bid & 15;
    int qt = (bid >> 4) & 31;
    int b  = bid >> 9;
    int Q0 = qt * 64;
    int kbase = Q0 - 127; if (kbase < 0) kbase = 0;
    int nk = Q0 + 64 - kbase;                       // 64..191 valid keys
    int tid = threadIdx.x;

    // ---- stage V transposed: Vt[dim][key], zero keys in [nk, VTS) ----
    // NOTE: guard is r < VTS (NOT more) — writing col >= VTS would alias the
    // next dim-row's first keys and race with their legit writes (round-3 bug).
    {
        int r32 = tid & 31;
        int c8  = (tid >> 5) * 8;
        #pragma unroll
        for (int p = 0; p < 7; ++p) {
            int r = p * 32 + r32;
            if (r < VTS) {
                unsigned int wv[4] = {0u, 0u, 0u, 0u};
                if (r < nk) {
                    uint4 v = *(const uint4*)(qkv +
                        (size_t)(b * 2048 + kbase + r) * 3072 + 2048 + h * 64 + c8);
                    wv[0] = v.x; wv[1] = v.y; wv[2] = v.z; wv[3] = v.w;
                }
                #pragma unroll
                for (int j = 0; j < 4; ++j) {
                    Vt[(c8 + 2 * j)     * VTS + r] = (unsigned short)(wv[j] & 0xffffu);
                    Vt[(c8 + 2 * j + 1) * VTS + r] = (unsigned short)(wv[j] >> 16);
                }
            }
        }
    }
    __syncthreads();

    int lane = tid & 63, w = tid >> 6;
    int qw0 = Q0 + w * 16;
    int lo = lane & 15, hi = lane >> 4;

    // ---- Q fragments (direct global) ----
    const unsigned short* qg =
        qkv + (size_t)(b * 2048 + qw0 + lo) * 3072 + h * 64 + hi * 8;
    bf16x8 aq0 = *(const bf16x8*)qg;
    bf16x8 aq1 = *(const bf16x8*)(qg + 32);

    // ---- key-tile range for this wave (even # of tiles when possible) ----
    int klo = qw0 - 127; if (klo < kbase) klo = kbase;
    int t0 = (klo - kbase) >> 4;
    int t1 = (qw0 + 15 - kbase) >> 4;
    int ntiles = t1 - t0 + 1;
    if ((ntiles & 1) && t0 > 0) { --t0; ++ntiles; }  // extra tile fully masked
    int nks = (ntiles + 1) >> 1;
    int wkb = t0 * 16;

    // ---- QK^T: S tiles (K frags direct from global) ----
    f32x4 s[10];
    #pragma unroll
    for (int i = 0; i < 10; ++i) s[i] = (f32x4){0.f, 0.f, 0.f, 0.f};
    #pragma unroll
    for (int i = 0; i < 10; ++i) {
        if (i < ntiles) {
            const unsigned short* kg = qkv +
                (size_t)(b * 2048 + kbase + (t0 + i) * 16 + lo) * 3072
                + 1024 + h * 64 + hi * 8;
            bf16x8 bk0 = *(const bf16x8*)kg;
            bf16x8 bk1 = *(const bf16x8*)(kg + 32);
            s[i] = __builtin_amdgcn_mfma_f32_16x16x32_bf16(aq0, bk0, s[i], 0, 0, 0);
            s[i] = __builtin_amdgcn_mfma_f32_16x16x32_bf16(aq1, bk1, s[i], 0, 0, 0);
        }
    }

    // ---- mask + softmax (rows = hi*4+r, cols = key) ----
    const float scale = 0.125f;                    // 1/sqrt(64)
    float mx[4] = {-1e30f, -1e30f, -1e30f, -1e30f};
    #pragma unroll
    for (int i = 0; i < 10; ++i) {
        if (i < ntiles) {
            int ka = kbase + (t0 + i) * 16 + lo;
            #pragma unroll
            for (int r = 0; r < 4; ++r) {
                int rel = (qw0 + hi * 4 + r) - ka;
                bool ok = (rel >= 0) && (rel < 128);
                float v = ok ? s[i][r] * scale : -1e30f;
                s[i][r] = v;
                mx[r] = fmaxf(mx[r], v);
            }
        }
    }
    #pragma unroll
    for (int r = 0; r < 4; ++r)
        #pragma unroll
        for (int o = 1; o < 16; o <<= 1)
            mx[r] = fmaxf(mx[r], __shfl_xor(mx[r], o));

    float sum[4] = {0.f, 0.f, 0.f, 0.f};
    #pragma unroll
    for (int i = 0; i < 10; ++i) {
        if (i < ntiles) {
            #pragma unroll
            for (int r = 0; r < 4; ++r) {
                float e = __expf(s[i][r] - mx[r]);
                s[i][r] = e;
                sum[r] += e;
            }
        }
    }
    #pragma unroll
    for (int r = 0; r < 4; ++r) {
        #pragma unroll
        for (int o = 1; o < 16; o <<= 1)
            sum[r] += __shfl_xor(sum[r], o);
        sum[r] = 1.0f / sum[r];
    }

    // ---- normalized P -> LDS (bf16) ----
    unsigned short* pw = &Ps[(w * 16) * PSS];
    #pragma unroll
    for (int i = 0; i < 10; ++i) {
        if (i < ntiles) {
            #pragma unroll
            for (int r = 0; r < 4; ++r)
                pw[(hi * 4 + r) * PSS + i * 16 + lo] = f2bf(s[i][r] * sum[r]);
        }
    }
    if (ntiles & 1) {                              // zero the pad stripe
        int zr = lane >> 2, zc = ntiles * 16 + (lane & 3) * 4;
        *(ushort4*)&pw[zr * PSS + zc] = (ushort4){0, 0, 0, 0};
    }

    // ---- PV: O[16q][64d] = P @ V ----
    f32x4 o[4];
    #pragma unroll
    for (int dt = 0; dt < 4; ++dt) o[dt] = (f32x4){0.f, 0.f, 0.f, 0.f};
    #pragma unroll
    for (int ks = 0; ks < 5; ++ks) {
        if (ks < nks) {
            bf16x8 pa = *(const bf16x8*)&Ps[(w * 16 + lo) * PSS + ks * 32 + hi * 8];
            #pragma unroll
            for (int dt = 0; dt < 4; ++dt) {
                bf16x8 vb = *(const bf16x8*)&Vt[(dt * 16 + lo) * VTS
                                                + wkb + ks * 32 + hi * 8];
                o[dt] = __builtin_amdgcn_mfma_f32_16x16x32_bf16(pa, vb, o[dt], 0, 0, 0);
            }
        }
    }

    // ---- store O (D-layout: col=dim=lo, row=hi*4+r) ----
    #pragma unroll
    for (int dt = 0; dt < 4; ++dt)
        #pragma unroll
        for (int r = 0; r < 4; ++r)
            aout[(size_t)(b * 2048 + qw0 + hi * 4 + r) * 1024
                 + h * 64 + dt * 16 + lo] = f2bf(o[dt][r]);
}

// ---------------------------------------------------------------------------
extern "C" void kernel_launch(void* const* d_in, const int* in_sizes, int n_in,
                              void* d_out, int out_size, void* d_ws, size_t ws_size,
                              hipStream_t stream) {
    const float* x     = (const float*)d_in[0];  // [2,2048,1024] fp32
    const float* Wqkv  = (const float*)d_in[1];  // [1024,3072]  fp32
    const float* bqkv  = (const float*)d_in[2];  // [3072]       fp32
    const float* Wproj = (const float*)d_in[3];  // [1024,1024]  fp32
    const float* bproj = (const float*)d_in[4];  // [1024]       fp32
    float* out = (float*)d_out;                  // [2,2048,1024] fp32

    char* ws = (char*)d_ws;
    unsigned short* WqkvT  = (unsigned short*)(ws);                // bf16 3072x1024:  6291456 B
    unsigned short* WprojT = (unsigned short*)(ws + 6291456);      // bf16 1024x1024:  2097152 B
    unsigned short* xb     = (unsigned short*)(ws + 8388608);      // bf16 4096x1024:  8388608 B
    unsigned short* qkv    = (unsigned short*)(ws + 16777216);     // bf16 4096x3072: 25165824 B
    float*          tab    = (float*)        (ws + 41943040);      // f32 2048x32x2:    524288 B
    unsigned short* attno  = (unsigned short*)(ws + 42467328);     // bf16 4096x1024:  8388608 B

    transpose_f32_bf16<<<dim3(96, 32), dim3(32, 8), 0, stream>>>(Wqkv,  WqkvT,  1024, 3072);
    transpose_f32_bf16<<<dim3(32, 32), dim3(32, 8), 0, stream>>>(Wproj, WprojT, 1024, 1024);
    f32_to_bf16_kernel<<<1024, 256, 0, stream>>>(x, xb, 4194304 / 4);
    rope_table_kernel<<<256, 256, 0, stream>>>(tab);

    gemm_bt<true><<<dim3(24, 32), 256, 0, stream>>>(xb, WqkvT, bqkv, qkv, 4096, 3072, 1024);
    rope_apply_kernel<<<16384, 256, 0, stream>>>(qkv, tab);
    attn_kernel<<<1024, 256, 0, stream>>>(qkv, attno);
    gemm_bt<false><<<dim3(8, 32), 256, 0, stream>>>(attno, WprojT, bproj, out, 4096, 1024, 1024);
}

// Round 5
// 115.987 us; speedup vs baseline: 1.7414x; 1.0550x over previous
//
#include <hip/hip_runtime.h>

// ---------------------------------------------------------------------------
// LocalCausalSelfAttention: x@Wqkv+b -> RoPE(q,k) -> windowed causal attn
// -> @Wproj+b.  B=2 T=2048 C=1024 H=16 Dh=64 W=128.
// External I/O: fp32. Internal: bf16 MFMA compute.
// ---------------------------------------------------------------------------

using bf16x8 = short  __attribute__((ext_vector_type(8)));
using f32x4  = float __attribute__((ext_vector_type(4)));

__device__ __forceinline__ float bf2f(unsigned short u) {
    return __uint_as_float(((unsigned int)u) << 16);
}
__device__ __forceinline__ unsigned short f2bf(float f) {
    unsigned int u = __float_as_uint(f);
    u += 0x7fffu + ((u >> 16) & 1u);      // RNE
    return (unsigned short)(u >> 16);
}

// async global->LDS, 16B per lane; LDS dest = uniform base + lane*16 (m97/m104)
__device__ __forceinline__ void gload_lds16(const unsigned short* g,
                                            unsigned short* l) {
    __builtin_amdgcn_global_load_lds(
        (const __attribute__((address_space(1))) unsigned int*)(g),
        (__attribute__((address_space(3))) unsigned int*)(l),
        16, 0, 0);
}

// ---------------- fp32 -> bf16 elementwise (vectorized) ---------------------
__global__ __launch_bounds__(256) void f32_to_bf16_kernel(
        const float* __restrict__ in, unsigned short* __restrict__ out, int n4) {
    int i = blockIdx.x * 256 + threadIdx.x;
    int stride = gridDim.x * 256;
    for (; i < n4; i += stride) {
        float4 v = ((const float4*)in)[i];
        ushort4 o;
        o.x = f2bf(v.x); o.y = f2bf(v.y); o.z = f2bf(v.z); o.w = f2bf(v.w);
        ((ushort4*)out)[i] = o;
    }
}

// ---------------- transpose + downcast (fp32 KxN -> bf16 NxK) ---------------
__global__ __launch_bounds__(256) void transpose_f32_bf16(
        const float* __restrict__ W, unsigned short* __restrict__ WT,
        int rows, int cols) {
    __shared__ unsigned short tile[32][33];
    int c0 = blockIdx.x * 32, r0 = blockIdx.y * 32;
    int tx = threadIdx.x, ty = threadIdx.y;
    for (int i = ty; i < 32; i += 8)
        tile[i][tx] = f2bf(W[(size_t)(r0 + i) * cols + c0 + tx]);
    __syncthreads();
    for (int i = ty; i < 32; i += 8)
        WT[(size_t)(c0 + i) * rows + r0 + tx] = tile[tx][i];
}

// ---------------- GEMM: C[M,N] = A[M,K] @ Bt[N,K]^T + bias ------------------
// m97 structure: linear LDS tiles [rows][32], global_load_lds width=16,
// 2 barriers per K-step (BK=32), 256 threads = 4 waves.
// Wave grid (BM/WM)x(BN/WN) must equal 4.
template <int BM, int BN, int WM, int WN, bool OUT_BF16>
__global__ __launch_bounds__(256) void gemm_lds(
        const unsigned short* __restrict__ A,
        const unsigned short* __restrict__ Bt,
        const float* __restrict__ bias,
        void* __restrict__ Cv,
        int M, int N, int K) {
    constexpr int MI = BM / 16;       // A staging instrs per K-step
    constexpr int NI = BN / 16;       // B staging instrs per K-step
    constexpr int PW = (MI + NI) / 4; // per wave
    constexpr int WGN = BN / WN;
    constexpr int MR = WM / 16, NR = WN / 16;

    __shared__ unsigned short As[BM * 32];
    __shared__ unsigned short Bs[BN * 32];

    int row0 = blockIdx.y * BM, col0 = blockIdx.x * BN;
    int tid = threadIdx.x;
    int lane = tid & 63, wid = tid >> 6;
    int wr = wid / WGN, wc = wid % WGN;
    int fr = lane & 15, kq = lane >> 4;
    int r_in = lane >> 2, cg8 = (lane & 3) * 8;   // staging: 16 rows x 4 chunks

    f32x4 acc[MR][NR];
    #pragma unroll
    for (int i = 0; i < MR; ++i)
        #pragma unroll
        for (int j = 0; j < NR; ++j)
            acc[i][j] = (f32x4){0.f, 0.f, 0.f, 0.f};

    for (int kt = 0; kt < K; kt += 32) {
        __syncthreads();                           // prev compute done reading
        #pragma unroll
        for (int t = 0; t < PW; ++t) {
            int j = wid * PW + t;                  // wave-uniform
            if (j < MI) {
                int row = j * 16 + r_in;
                gload_lds16(A + (size_t)(row0 + row) * K + kt + cg8,
                            &As[j * 512]);
            } else {
                int jb = j - MI;
                int row = jb * 16 + r_in;
                gload_lds16(Bt + (size_t)(col0 + row) * K + kt + cg8,
                            &Bs[jb * 512]);
            }
        }
        __syncthreads();                           // drains vmcnt -> data ready

        bf16x8 af[MR], bfv[NR];
        #pragma unroll
        for (int i = 0; i < MR; ++i)
            af[i] = *(const bf16x8*)&As[(wr * WM + i * 16 + fr) * 32 + kq * 8];
        #pragma unroll
        for (int j = 0; j < NR; ++j)
            bfv[j] = *(const bf16x8*)&Bs[(wc * WN + j * 16 + fr) * 32 + kq * 8];
        #pragma unroll
        for (int i = 0; i < MR; ++i)
            #pragma unroll
            for (int j = 0; j < NR; ++j)
                acc[i][j] = __builtin_amdgcn_mfma_f32_16x16x32_bf16(
                                af[i], bfv[j], acc[i][j], 0, 0, 0);
    }

    int rg = kq * 4;
    #pragma unroll
    for (int j = 0; j < NR; ++j) {
        int col = col0 + wc * WN + j * 16 + fr;
        float bz = bias[col];
        #pragma unroll
        for (int i = 0; i < MR; ++i) {
            #pragma unroll
            for (int r = 0; r < 4; ++r) {
                int row = row0 + wr * WM + i * 16 + rg + r;
                float val = acc[i][j][r] + bz;
                if constexpr (OUT_BF16)
                    ((unsigned short*)Cv)[(size_t)row * N + col] = f2bf(val);
                else
                    ((float*)Cv)[(size_t)row * N + col] = val;
            }
        }
    }
}

// ---------------- RoPE table ------------------------------------------------
__global__ __launch_bounds__(256) void rope_table_kernel(float* __restrict__ tab) {
    int idx = blockIdx.x * 256 + threadIdx.x;   // 65536 = 2048*32
    int t = idx >> 5, i = idx & 31;
    float inv = powf(10000.0f, -(float)i / 32.0f);
    float ang = (float)t * inv;
    tab[idx * 2]     = cosf(ang);
    tab[idx * 2 + 1] = sinf(ang);
}

// ---------------- RoPE apply (in-place on bf16 q,k halves of qkv) -----------
__global__ __launch_bounds__(256) void rope_apply_kernel(
        unsigned short* __restrict__ qkv, const float* __restrict__ tab) {
    int idx = blockIdx.x * 256 + threadIdx.x;   // 4194304 pairs
    int p = idx & 1023; int row = idx >> 10;
    int t = row & 2047;
    int sel = p >> 9;
    int hp = p & 511; int h = hp >> 5; int i = hp & 31;
    int col = sel * 1024 + h * 64 + 2 * i;
    unsigned int* addr = (unsigned int*)(qkv + (size_t)row * 3072 + col);
    unsigned int u = *addr;
    float x0 = __uint_as_float(u << 16);
    float x1 = __uint_as_float(u & 0xffff0000u);
    float c = tab[(t * 32 + i) * 2];
    float s = tab[(t * 32 + i) * 2 + 1];
    float y0 = x0 * c - x1 * s;
    float y1 = x1 * c + x0 * s;
    *addr = (unsigned int)f2bf(y0) | ((unsigned int)f2bf(y1) << 16);
}

// ---------------- MFMA windowed causal attention ----------------------------
// Block = (b, h, 64-query tile), 4 waves, wave owns 16 queries.
#define VTS 200   // Vt col stride (keys): mult of 8 (16B align), 2-way banks
#define PSS 168   // P row stride: mult of 8, 2-way banks, >= 160

__global__ __launch_bounds__(256) void attn_kernel(
        const unsigned short* __restrict__ qkv, unsigned short* __restrict__ aout) {
    __shared__ unsigned short Vt[64 * VTS];        // 25600 B
    __shared__ unsigned short Ps[4 * 16 * PSS];    // 21504 B

    int bid = blockIdx.x;
    int h  = bid & 15;
    int qt = (bid >> 4) & 31;
    int b  = bid >> 9;
    int Q0 = qt * 64;
    int kbase = Q0 - 127; if (kbase < 0) kbase = 0;
    int nk = Q0 + 64 - kbase;                       // 64..191 valid keys
    int tid = threadIdx.x;

    // ---- stage V transposed: Vt[dim][key], zero keys in [nk, VTS) ----
    {
        int r32 = tid & 31;
        int c8  = (tid >> 5) * 8;
        #pragma unroll
        for (int p = 0; p < 7; ++p) {
            int r = p * 32 + r32;
            if (r < VTS) {
                unsigned int wv[4] = {0u, 0u, 0u, 0u};
                if (r < nk) {
                    uint4 v = *(const uint4*)(qkv +
                        (size_t)(b * 2048 + kbase + r) * 3072 + 2048 + h * 64 + c8);
                    wv[0] = v.x; wv[1] = v.y; wv[2] = v.z; wv[3] = v.w;
                }
                #pragma unroll
                for (int j = 0; j < 4; ++j) {
                    Vt[(c8 + 2 * j)     * VTS + r] = (unsigned short)(wv[j] & 0xffffu);
                    Vt[(c8 + 2 * j + 1) * VTS + r] = (unsigned short)(wv[j] >> 16);
                }
            }
        }
    }
    __syncthreads();

    int lane = tid & 63, w = tid >> 6;
    int qw0 = Q0 + w * 16;
    int lo = lane & 15, hi = lane >> 4;

    // ---- Q fragments (direct global) ----
    const unsigned short* qg =
        qkv + (size_t)(b * 2048 + qw0 + lo) * 3072 + h * 64 + hi * 8;
    bf16x8 aq0 = *(const bf16x8*)qg;
    bf16x8 aq1 = *(const bf16x8*)(qg + 32);

    // ---- key-tile range for this wave (even # of tiles when possible) ----
    int klo = qw0 - 127; if (klo < kbase) klo = kbase;
    int t0 = (klo - kbase) >> 4;
    int t1 = (qw0 + 15 - kbase) >> 4;
    int ntiles = t1 - t0 + 1;
    if ((ntiles & 1) && t0 > 0) { --t0; ++ntiles; }  // extra tile fully masked
    int nks = (ntiles + 1) >> 1;
    int wkb = t0 * 16;

    // ---- QK^T: S tiles (K frags direct from global) ----
    f32x4 s[10];
    #pragma unroll
    for (int i = 0; i < 10; ++i) s[i] = (f32x4){0.f, 0.f, 0.f, 0.f};
    #pragma unroll
    for (int i = 0; i < 10; ++i) {
        if (i < ntiles) {
            const unsigned short* kg = qkv +
                (size_t)(b * 2048 + kbase + (t0 + i) * 16 + lo) * 3072
                + 1024 + h * 64 + hi * 8;
            bf16x8 bk0 = *(const bf16x8*)kg;
            bf16x8 bk1 = *(const bf16x8*)(kg + 32);
            s[i] = __builtin_amdgcn_mfma_f32_16x16x32_bf16(aq0, bk0, s[i], 0, 0, 0);
            s[i] = __builtin_amdgcn_mfma_f32_16x16x32_bf16(aq1, bk1, s[i], 0, 0, 0);
        }
    }

    // ---- mask + softmax (rows = hi*4+r, cols = key) ----
    const float scale = 0.125f;                    // 1/sqrt(64)
    float mx[4] = {-1e30f, -1e30f, -1e30f, -1e30f};
    #pragma unroll
    for (int i = 0; i < 10; ++i) {
        if (i < ntiles) {
            int ka = kbase + (t0 + i) * 16 + lo;
            #pragma unroll
            for (int r = 0; r < 4; ++r) {
                int rel = (qw0 + hi * 4 + r) - ka;
                bool ok = (rel >= 0) && (rel < 128);
                float v = ok ? s[i][r] * scale : -1e30f;
                s[i][r] = v;
                mx[r] = fmaxf(mx[r], v);
            }
        }
    }
    #pragma unroll
    for (int r = 0; r < 4; ++r)
        #pragma unroll
        for (int o = 1; o < 16; o <<= 1)
            mx[r] = fmaxf(mx[r], __shfl_xor(mx[r], o));

    float sum[4] = {0.f, 0.f, 0.f, 0.f};
    #pragma unroll
    for (int i = 0; i < 10; ++i) {
        if (i < ntiles) {
            #pragma unroll
            for (int r = 0; r < 4; ++r) {
                float e = __expf(s[i][r] - mx[r]);
                s[i][r] = e;
                sum[r] += e;
            }
        }
    }
    #pragma unroll
    for (int r = 0; r < 4; ++r) {
        #pragma unroll
        for (int o = 1; o < 16; o <<= 1)
            sum[r] += __shfl_xor(sum[r], o);
        sum[r] = 1.0f / sum[r];
    }

    // ---- normalized P -> LDS (bf16) ----
    unsigned short* pw = &Ps[(w * 16) * PSS];
    #pragma unroll
    for (int i = 0; i < 10; ++i) {
        if (i < ntiles) {
            #pragma unroll
            for (int r = 0; r < 4; ++r)
                pw[(hi * 4 + r) * PSS + i * 16 + lo] = f2bf(s[i][r] * sum[r]);
        }
    }
    if (ntiles & 1) {                              // zero the pad stripe
        int zr = lane >> 2, zc = ntiles * 16 + (lane & 3) * 4;
        *(ushort4*)&pw[zr * PSS + zc] = (ushort4){0, 0, 0, 0};
    }

    // ---- PV: O[16q][64d] = P @ V ----
    f32x4 o[4];
    #pragma unroll
    for (int dt = 0; dt < 4; ++dt) o[dt] = (f32x4){0.f, 0.f, 0.f, 0.f};
    #pragma unroll
    for (int ks = 0; ks < 5; ++ks) {
        if (ks < nks) {
            bf16x8 pa = *(const bf16x8*)&Ps[(w * 16 + lo) * PSS + ks * 32 + hi * 8];
            #pragma unroll
            for (int dt = 0; dt < 4; ++dt) {
                bf16x8 vb = *(const bf16x8*)&Vt[(dt * 16 + lo) * VTS
                                                + wkb + ks * 32 + hi * 8];
                o[dt] = __builtin_amdgcn_mfma_f32_16x16x32_bf16(pa, vb, o[dt], 0, 0, 0);
            }
        }
    }

    // ---- store O (D-layout: col=dim=lo, row=hi*4+r) ----
    #pragma unroll
    for (int dt = 0; dt < 4; ++dt)
        #pragma unroll
        for (int r = 0; r < 4; ++r)
            aout[(size_t)(b * 2048 + qw0 + hi * 4 + r) * 1024
                 + h * 64 + dt * 16 + lo] = f2bf(o[dt][r]);
}

// ---------------------------------------------------------------------------
extern "C" void kernel_launch(void* const* d_in, const int* in_sizes, int n_in,
                              void* d_out, int out_size, void* d_ws, size_t ws_size,
                              hipStream_t stream) {
    const float* x     = (const float*)d_in[0];  // [2,2048,1024] fp32
    const float* Wqkv  = (const float*)d_in[1];  // [1024,3072]  fp32
    const float* bqkv  = (const float*)d_in[2];  // [3072]       fp32
    const float* Wproj = (const float*)d_in[3];  // [1024,1024]  fp32
    const float* bproj = (const float*)d_in[4];  // [1024]       fp32
    float* out = (float*)d_out;                  // [2,2048,1024] fp32

    char* ws = (char*)d_ws;
    unsigned short* WqkvT  = (unsigned short*)(ws);                // bf16 3072x1024:  6291456 B
    unsigned short* WprojT = (unsigned short*)(ws + 6291456);      // bf16 1024x1024:  2097152 B
    unsigned short* xb     = (unsigned short*)(ws + 8388608);      // bf16 4096x1024:  8388608 B
    unsigned short* qkv    = (unsigned short*)(ws + 16777216);     // bf16 4096x3072: 25165824 B
    float*          tab    = (float*)        (ws + 41943040);      // f32 2048x32x2:    524288 B
    unsigned short* attno  = (unsigned short*)(ws + 42467328);     // bf16 4096x1024:  8388608 B

    transpose_f32_bf16<<<dim3(96, 32), dim3(32, 8), 0, stream>>>(Wqkv,  WqkvT,  1024, 3072);
    transpose_f32_bf16<<<dim3(32, 32), dim3(32, 8), 0, stream>>>(Wproj, WprojT, 1024, 1024);
    f32_to_bf16_kernel<<<1024, 256, 0, stream>>>(x, xb, 4194304 / 4);
    rope_table_kernel<<<256, 256, 0, stream>>>(tab);

    // qkv = xb @ WqkvT^T + bqkv   (bf16 out)  128x128 tile, 768 blocks
    gemm_lds<128, 128, 64, 64, true>
        <<<dim3(24, 32), 256, 0, stream>>>(xb, WqkvT, bqkv, qkv, 4096, 3072, 1024);
    rope_apply_kernel<<<16384, 256, 0, stream>>>(qkv, tab);
    attn_kernel<<<1024, 256, 0, stream>>>(qkv, attno);
    // out = attno @ WprojT^T + bproj (fp32 out) 128x64 tile, 512 blocks
    gemm_lds<128, 64, 32, 64, false>
        <<<dim3(16, 32), 256, 0, stream>>>(attno, WprojT, bproj, out, 4096, 1024, 1024);
}

// Round 6
// 114.802 us; speedup vs baseline: 1.7594x; 1.0103x over previous
//
#include <hip/hip_runtime.h>

// ---------------------------------------------------------------------------
// LocalCausalSelfAttention: x@Wqkv+b -> RoPE(q,k) -> windowed causal attn
// -> @Wproj+b.  B=2 T=2048 C=1024 H=16 Dh=64 W=128.
// External I/O: fp32. Internal: bf16 MFMA compute.
// ---------------------------------------------------------------------------

using bf16x8 = short  __attribute__((ext_vector_type(8)));
using f32x4  = float __attribute__((ext_vector_type(4)));

__device__ __forceinline__ float bf2f(unsigned short u) {
    return __uint_as_float(((unsigned int)u) << 16);
}
__device__ __forceinline__ unsigned short f2bf(float f) {
    unsigned int u = __float_as_uint(f);
    u += 0x7fffu + ((u >> 16) & 1u);      // RNE
    return (unsigned short)(u >> 16);
}

// async global->LDS, 16B per lane; LDS dest = uniform base + lane*16 (m97/m104)
__device__ __forceinline__ void gload_lds16(const unsigned short* g,
                                            unsigned short* l) {
    __builtin_amdgcn_global_load_lds(
        (const __attribute__((address_space(1))) unsigned int*)(g),
        (__attribute__((address_space(3))) unsigned int*)(l),
        16, 0, 0);
}

// ---------------- fp32 -> bf16 elementwise (vectorized) ---------------------
__global__ __launch_bounds__(256) void f32_to_bf16_kernel(
        const float* __restrict__ in, unsigned short* __restrict__ out, int n4) {
    int i = blockIdx.x * 256 + threadIdx.x;
    int stride = gridDim.x * 256;
    for (; i < n4; i += stride) {
        float4 v = ((const float4*)in)[i];
        ushort4 o;
        o.x = f2bf(v.x); o.y = f2bf(v.y); o.z = f2bf(v.z); o.w = f2bf(v.w);
        ((ushort4*)out)[i] = o;
    }
}

// ---------------- transpose + downcast (fp32 KxN -> bf16 NxK) ---------------
__global__ __launch_bounds__(256) void transpose_f32_bf16(
        const float* __restrict__ W, unsigned short* __restrict__ WT,
        int rows, int cols) {
    __shared__ unsigned short tile[32][33];
    int c0 = blockIdx.x * 32, r0 = blockIdx.y * 32;
    int tx = threadIdx.x, ty = threadIdx.y;
    for (int i = ty; i < 32; i += 8)
        tile[i][tx] = f2bf(W[(size_t)(r0 + i) * cols + c0 + tx]);
    __syncthreads();
    for (int i = ty; i < 32; i += 8)
        WT[(size_t)(c0 + i) * rows + r0 + tx] = tile[tx][i];
}

// ---------------- GEMM: C[M,N] = A[M,K] @ Bt[N,K]^T + bias ------------------
// m97 LDS layout + T3 "minimum 2-phase" pipeline: double-buffered linear LDS
// tiles [rows][32], global_load_lds width=16, prefetch tile k+1 issued BEFORE
// computing tile k, ONE __syncthreads() per K-step (its implicit vmcnt(0)
// drain lands after the MFMAs -> load latency hides under compute).
// Wave grid (BM/WM)x(BN/WN) must equal 4.
template <int BM, int BN, int WM, int WN, bool OUT_BF16>
__global__ __launch_bounds__(256) void gemm_lds(
        const unsigned short* __restrict__ A,
        const unsigned short* __restrict__ Bt,
        const float* __restrict__ bias,
        void* __restrict__ Cv,
        int M, int N, int K) {
    constexpr int MI = BM / 16;       // A staging instrs per K-step
    constexpr int NI = BN / 16;       // B staging instrs per K-step
    constexpr int PW = (MI + NI) / 4; // per wave
    constexpr int WGN = BN / WN;
    constexpr int MR = WM / 16, NR = WN / 16;

    __shared__ unsigned short As[2][BM * 32];
    __shared__ unsigned short Bs[2][BN * 32];

    int row0 = blockIdx.y * BM, col0 = blockIdx.x * BN;
    int tid = threadIdx.x;
    int lane = tid & 63, wid = tid >> 6;
    int wr = wid / WGN, wc = wid % WGN;
    int fr = lane & 15, kq = lane >> 4;
    int r_in = lane >> 2, cg8 = (lane & 3) * 8;   // staging: 16 rows x 4 chunks

    f32x4 acc[MR][NR];
    #pragma unroll
    for (int i = 0; i < MR; ++i)
        #pragma unroll
        for (int j = 0; j < NR; ++j)
            acc[i][j] = (f32x4){0.f, 0.f, 0.f, 0.f};

    // stage K-tile kt into buffer buf
    auto stage = [&](int buf, int kt) {
        #pragma unroll
        for (int t = 0; t < PW; ++t) {
            int j = wid * PW + t;                  // wave-uniform
            if (j < MI) {
                int row = j * 16 + r_in;
                gload_lds16(A + (size_t)(row0 + row) * K + kt + cg8,
                            &As[buf][j * 512]);
            } else {
                int jb = j - MI;
                int row = jb * 16 + r_in;
                gload_lds16(Bt + (size_t)(col0 + row) * K + kt + cg8,
                            &Bs[buf][jb * 512]);
            }
        }
    };
    // compute one K-step from buffer buf
    auto compute = [&](int buf) {
        bf16x8 af[MR], bfv[NR];
        #pragma unroll
        for (int i = 0; i < MR; ++i)
            af[i] = *(const bf16x8*)&As[buf][(wr * WM + i * 16 + fr) * 32 + kq * 8];
        #pragma unroll
        for (int j = 0; j < NR; ++j)
            bfv[j] = *(const bf16x8*)&Bs[buf][(wc * WN + j * 16 + fr) * 32 + kq * 8];
        #pragma unroll
        for (int i = 0; i < MR; ++i)
            #pragma unroll
            for (int j = 0; j < NR; ++j)
                acc[i][j] = __builtin_amdgcn_mfma_f32_16x16x32_bf16(
                                af[i], bfv[j], acc[i][j], 0, 0, 0);
    };

    stage(0, 0);
    __syncthreads();                               // drains vmcnt -> buf0 ready
    int cur = 0;
    for (int kt = 32; kt < K; kt += 32) {
        stage(cur ^ 1, kt);                        // prefetch next (async)
        compute(cur);                              // overlap with loads
        __syncthreads();                           // drain + separate buffers
        cur ^= 1;
    }
    compute(cur);                                  // last tile, no prefetch

    int rg = kq * 4;
    #pragma unroll
    for (int j = 0; j < NR; ++j) {
        int col = col0 + wc * WN + j * 16 + fr;
        float bz = bias[col];
        #pragma unroll
        for (int i = 0; i < MR; ++i) {
            #pragma unroll
            for (int r = 0; r < 4; ++r) {
                int row = row0 + wr * WM + i * 16 + rg + r;
                float val = acc[i][j][r] + bz;
                if constexpr (OUT_BF16)
                    ((unsigned short*)Cv)[(size_t)row * N + col] = f2bf(val);
                else
                    ((float*)Cv)[(size_t)row * N + col] = val;
            }
        }
    }
}

// ---------------- RoPE table ------------------------------------------------
__global__ __launch_bounds__(256) void rope_table_kernel(float* __restrict__ tab) {
    int idx = blockIdx.x * 256 + threadIdx.x;   // 65536 = 2048*32
    int t = idx >> 5, i = idx & 31;
    float inv = powf(10000.0f, -(float)i / 32.0f);
    float ang = (float)t * inv;
    tab[idx * 2]     = cosf(ang);
    tab[idx * 2 + 1] = sinf(ang);
}

// ---------------- RoPE apply (in-place on bf16 q,k halves of qkv) -----------
__global__ __launch_bounds__(256) void rope_apply_kernel(
        unsigned short* __restrict__ qkv, const float* __restrict__ tab) {
    int idx = blockIdx.x * 256 + threadIdx.x;   // 4194304 pairs
    int p = idx & 1023; int row = idx >> 10;
    int t = row & 2047;
    int sel = p >> 9;
    int hp = p & 511; int h = hp >> 5; int i = hp & 31;
    int col = sel * 1024 + h * 64 + 2 * i;
    unsigned int* addr = (unsigned int*)(qkv + (size_t)row * 3072 + col);
    unsigned int u = *addr;
    float x0 = __uint_as_float(u << 16);
    float x1 = __uint_as_float(u & 0xffff0000u);
    float c = tab[(t * 32 + i) * 2];
    float s = tab[(t * 32 + i) * 2 + 1];
    float y0 = x0 * c - x1 * s;
    float y1 = x1 * c + x0 * s;
    *addr = (unsigned int)f2bf(y0) | ((unsigned int)f2bf(y1) << 16);
}

// ---------------- MFMA windowed causal attention ----------------------------
// Block = (b, h, 64-query tile), 4 waves, wave owns 16 queries.
#define VTS 200   // Vt col stride (keys): mult of 8 (16B align), 2-way banks
#define PSS 168   // P row stride: mult of 8, 2-way banks, >= 160

__global__ __launch_bounds__(256) void attn_kernel(
        const unsigned short* __restrict__ qkv, unsigned short* __restrict__ aout) {
    __shared__ unsigned short Vt[64 * VTS];        // 25600 B
    __shared__ unsigned short Ps[4 * 16 * PSS];    // 21504 B

    int bid = blockIdx.x;
    int h  = bid & 15;
    int qt = (bid >> 4) & 31;
    int b  = bid >> 9;
    int Q0 = qt * 64;
    int kbase = Q0 - 127; if (kbase < 0) kbase = 0;
    int nk = Q0 + 64 - kbase;                       // 64..191 valid keys
    int tid = threadIdx.x;

    // ---- stage V transposed: Vt[dim][key], zero keys in [nk, VTS) ----
    {
        int r32 = tid & 31;
        int c8  = (tid >> 5) * 8;
        #pragma unroll
        for (int p = 0; p < 7; ++p) {
            int r = p * 32 + r32;
            if (r < VTS) {
                unsigned int wv[4] = {0u, 0u, 0u, 0u};
                if (r < nk) {
                    uint4 v = *(const uint4*)(qkv +
                        (size_t)(b * 2048 + kbase + r) * 3072 + 2048 + h * 64 + c8);
                    wv[0] = v.x; wv[1] = v.y; wv[2] = v.z; wv[3] = v.w;
                }
                #pragma unroll
                for (int j = 0; j < 4; ++j) {
                    Vt[(c8 + 2 * j)     * VTS + r] = (unsigned short)(wv[j] & 0xffffu);
                    Vt[(c8 + 2 * j + 1) * VTS + r] = (unsigned short)(wv[j] >> 16);
                }
            }
        }
    }
    __syncthreads();

    int lane = tid & 63, w = tid >> 6;
    int qw0 = Q0 + w * 16;
    int lo = lane & 15, hi = lane >> 4;

    // ---- Q fragments (direct global) ----
    const unsigned short* qg =
        qkv + (size_t)(b * 2048 + qw0 + lo) * 3072 + h * 64 + hi * 8;
    bf16x8 aq0 = *(const bf16x8*)qg;
    bf16x8 aq1 = *(const bf16x8*)(qg + 32);

    // ---- key-tile range for this wave (even # of tiles when possible) ----
    int klo = qw0 - 127; if (klo < kbase) klo = kbase;
    int t0 = (klo - kbase) >> 4;
    int t1 = (qw0 + 15 - kbase) >> 4;
    int ntiles = t1 - t0 + 1;
    if ((ntiles & 1) && t0 > 0) { --t0; ++ntiles; }  // extra tile fully masked
    int nks = (ntiles + 1) >> 1;
    int wkb = t0 * 16;

    // ---- QK^T: S tiles (K frags direct from global) ----
    f32x4 s[10];
    #pragma unroll
    for (int i = 0; i < 10; ++i) s[i] = (f32x4){0.f, 0.f, 0.f, 0.f};
    #pragma unroll
    for (int i = 0; i < 10; ++i) {
        if (i < ntiles) {
            const unsigned short* kg = qkv +
                (size_t)(b * 2048 + kbase + (t0 + i) * 16 + lo) * 3072
                + 1024 + h * 64 + hi * 8;
            bf16x8 bk0 = *(const bf16x8*)kg;
            bf16x8 bk1 = *(const bf16x8*)(kg + 32);
            s[i] = __builtin_amdgcn_mfma_f32_16x16x32_bf16(aq0, bk0, s[i], 0, 0, 0);
            s[i] = __builtin_amdgcn_mfma_f32_16x16x32_bf16(aq1, bk1, s[i], 0, 0, 0);
        }
    }

    // ---- mask + softmax (rows = hi*4+r, cols = key) ----
    const float scale = 0.125f;                    // 1/sqrt(64)
    float mx[4] = {-1e30f, -1e30f, -1e30f, -1e30f};
    #pragma unroll
    for (int i = 0; i < 10; ++i) {
        if (i < ntiles) {
            int ka = kbase + (t0 + i) * 16 + lo;
            #pragma unroll
            for (int r = 0; r < 4; ++r) {
                int rel = (qw0 + hi * 4 + r) - ka;
                bool ok = (rel >= 0) && (rel < 128);
                float v = ok ? s[i][r] * scale : -1e30f;
                s[i][r] = v;
                mx[r] = fmaxf(mx[r], v);
            }
        }
    }
    #pragma unroll
    for (int r = 0; r < 4; ++r)
        #pragma unroll
        for (int o = 1; o < 16; o <<= 1)
            mx[r] = fmaxf(mx[r], __shfl_xor(mx[r], o));

    float sum[4] = {0.f, 0.f, 0.f, 0.f};
    #pragma unroll
    for (int i = 0; i < 10; ++i) {
        if (i < ntiles) {
            #pragma unroll
            for (int r = 0; r < 4; ++r) {
                float e = __expf(s[i][r] - mx[r]);
                s[i][r] = e;
                sum[r] += e;
            }
        }
    }
    #pragma unroll
    for (int r = 0; r < 4; ++r) {
        #pragma unroll
        for (int o = 1; o < 16; o <<= 1)
            sum[r] += __shfl_xor(sum[r], o);
        sum[r] = 1.0f / sum[r];
    }

    // ---- normalized P -> LDS (bf16) ----
    unsigned short* pw = &Ps[(w * 16) * PSS];
    #pragma unroll
    for (int i = 0; i < 10; ++i) {
        if (i < ntiles) {
            #pragma unroll
            for (int r = 0; r < 4; ++r)
                pw[(hi * 4 + r) * PSS + i * 16 + lo] = f2bf(s[i][r] * sum[r]);
        }
    }
    if (ntiles & 1) {                              // zero the pad stripe
        int zr = lane >> 2, zc = ntiles * 16 + (lane & 3) * 4;
        *(ushort4*)&pw[zr * PSS + zc] = (ushort4){0, 0, 0, 0};
    }

    // ---- PV: O[16q][64d] = P @ V ----
    f32x4 o[4];
    #pragma unroll
    for (int dt = 0; dt < 4; ++dt) o[dt] = (f32x4){0.f, 0.f, 0.f, 0.f};
    #pragma unroll
    for (int ks = 0; ks < 5; ++ks) {
        if (ks < nks) {
            bf16x8 pa = *(const bf16x8*)&Ps[(w * 16 + lo) * PSS + ks * 32 + hi * 8];
            #pragma unroll
            for (int dt = 0; dt < 4; ++dt) {
                bf16x8 vb = *(const bf16x8*)&Vt[(dt * 16 + lo) * VTS
                                                + wkb + ks * 32 + hi * 8];
                o[dt] = __builtin_amdgcn_mfma_f32_16x16x32_bf16(pa, vb, o[dt], 0, 0, 0);
            }
        }
    }

    // ---- store O (D-layout: col=dim=lo, row=hi*4+r) ----
    #pragma unroll
    for (int dt = 0; dt < 4; ++dt)
        #pragma unroll
        for (int r = 0; r < 4; ++r)
            aout[(size_t)(b * 2048 + qw0 + hi * 4 + r) * 1024
                 + h * 64 + dt * 16 + lo] = f2bf(o[dt][r]);
}

// ---------------------------------------------------------------------------
extern "C" void kernel_launch(void* const* d_in, const int* in_sizes, int n_in,
                              void* d_out, int out_size, void* d_ws, size_t ws_size,
                              hipStream_t stream) {
    const float* x     = (const float*)d_in[0];  // [2,2048,1024] fp32
    const float* Wqkv  = (const float*)d_in[1];  // [1024,3072]  fp32
    const float* bqkv  = (const float*)d_in[2];  // [3072]       fp32
    const float* Wproj = (const float*)d_in[3];  // [1024,1024]  fp32
    const float* bproj = (const float*)d_in[4];  // [1024]       fp32
    float* out = (float*)d_out;                  // [2,2048,1024] fp32

    char* ws = (char*)d_ws;
    unsigned short* WqkvT  = (unsigned short*)(ws);                // bf16 3072x1024:  6291456 B
    unsigned short* WprojT = (unsigned short*)(ws + 6291456);      // bf16 1024x1024:  2097152 B
    unsigned short* xb     = (unsigned short*)(ws + 8388608);      // bf16 4096x1024:  8388608 B
    unsigned short* qkv    = (unsigned short*)(ws + 16777216);     // bf16 4096x3072: 25165824 B
    float*          tab    = (float*)        (ws + 41943040);      // f32 2048x32x2:    524288 B
    unsigned short* attno  = (unsigned short*)(ws + 42467328);     // bf16 4096x1024:  8388608 B

    transpose_f32_bf16<<<dim3(96, 32), dim3(32, 8), 0, stream>>>(Wqkv,  WqkvT,  1024, 3072);
    transpose_f32_bf16<<<dim3(32, 32), dim3(32, 8), 0, stream>>>(Wproj, WprojT, 1024, 1024);
    f32_to_bf16_kernel<<<1024, 256, 0, stream>>>(x, xb, 4194304 / 4);
    rope_table_kernel<<<256, 256, 0, stream>>>(tab);

    // qkv = xb @ WqkvT^T + bqkv   (bf16 out)  128x128 tile, 768 blocks
    gemm_lds<128, 128, 64, 64, true>
        <<<dim3(24, 32), 256, 0, stream>>>(xb, WqkvT, bqkv, qkv, 4096, 3072, 1024);
    rope_apply_kernel<<<16384, 256, 0, stream>>>(qkv, tab);
    attn_kernel<<<1024, 256, 0, stream>>>(qkv, attno);
    // out = attno @ WprojT^T + bproj (fp32 out) 128x64 tile, 512 blocks
    gemm_lds<128, 64, 32, 64, false>
        <<<dim3(16, 32), 256, 0, stream>>>(attno, WprojT, bproj, out, 4096, 1024, 1024);
}

// Round 7
// 109.366 us; speedup vs baseline: 1.8469x; 1.0497x over previous
//
#include <hip/hip_runtime.h>

// ---------------------------------------------------------------------------
// LocalCausalSelfAttention: x@Wqkv+b -> RoPE(q,k) -> windowed causal attn
// -> @Wproj+b.  B=2 T=2048 C=1024 H=16 Dh=64 W=128.
// External I/O: fp32. Internal: bf16 MFMA compute.
// RoPE is fused into GEMM1's epilogue (partner element via __shfl_xor(.,1)).
// ---------------------------------------------------------------------------

using bf16x8 = short  __attribute__((ext_vector_type(8)));
using f32x4  = float __attribute__((ext_vector_type(4)));

__device__ __forceinline__ float bf2f(unsigned short u) {
    return __uint_as_float(((unsigned int)u) << 16);
}
__device__ __forceinline__ unsigned short f2bf(float f) {
    unsigned int u = __float_as_uint(f);
    u += 0x7fffu + ((u >> 16) & 1u);      // RNE
    return (unsigned short)(u >> 16);
}

// async global->LDS, 16B per lane; LDS dest = uniform base + lane*16 (m97/m104)
__device__ __forceinline__ void gload_lds16(const unsigned short* g,
                                            unsigned short* l) {
    __builtin_amdgcn_global_load_lds(
        (const __attribute__((address_space(1))) unsigned int*)(g),
        (__attribute__((address_space(3))) unsigned int*)(l),
        16, 0, 0);
}

// ---------------- fp32 -> bf16 elementwise (vectorized) ---------------------
__global__ __launch_bounds__(256) void f32_to_bf16_kernel(
        const float* __restrict__ in, unsigned short* __restrict__ out, int n4) {
    int i = blockIdx.x * 256 + threadIdx.x;
    int stride = gridDim.x * 256;
    for (; i < n4; i += stride) {
        float4 v = ((const float4*)in)[i];
        ushort4 o;
        o.x = f2bf(v.x); o.y = f2bf(v.y); o.z = f2bf(v.z); o.w = f2bf(v.w);
        ((ushort4*)out)[i] = o;
    }
}

// ---------------- transpose + downcast (fp32 KxN -> bf16 NxK) ---------------
__global__ __launch_bounds__(256) void transpose_f32_bf16(
        const float* __restrict__ W, unsigned short* __restrict__ WT,
        int rows, int cols) {
    __shared__ unsigned short tile[32][33];
    int c0 = blockIdx.x * 32, r0 = blockIdx.y * 32;
    int tx = threadIdx.x, ty = threadIdx.y;
    for (int i = ty; i < 32; i += 8)
        tile[i][tx] = f2bf(W[(size_t)(r0 + i) * cols + c0 + tx]);
    __syncthreads();
    for (int i = ty; i < 32; i += 8)
        WT[(size_t)(c0 + i) * rows + r0 + tx] = tile[tx][i];
}

// ---------------- GEMM: C[M,N] = A[M,K] @ Bt[N,K]^T + bias ------------------
// m97 LDS layout + 2-phase dbuf pipeline (global_load_lds w=16, one barrier
// per K-step). Optional fused RoPE epilogue (GEMM1): for cols < 2048 (q,k)
// apply y = x*c -/+ partner*s, partner = __shfl_xor(x,1) (col^1 = lane fr^1).
// Wave grid (BM/WM)x(BN/WN) must equal 4.
template <int BM, int BN, int WM, int WN, bool OUT_BF16, bool FUSE_ROPE>
__global__ __launch_bounds__(256) void gemm_lds(
        const unsigned short* __restrict__ A,
        const unsigned short* __restrict__ Bt,
        const float* __restrict__ bias,
        void* __restrict__ Cv,
        const float* __restrict__ tab,
        int M, int N, int K) {
    constexpr int MI = BM / 16;       // A staging instrs per K-step
    constexpr int NI = BN / 16;       // B staging instrs per K-step
    constexpr int PW = (MI + NI) / 4; // per wave
    constexpr int WGN = BN / WN;
    constexpr int MR = WM / 16, NR = WN / 16;

    __shared__ unsigned short As[2][BM * 32];
    __shared__ unsigned short Bs[2][BN * 32];

    int row0 = blockIdx.y * BM, col0 = blockIdx.x * BN;
    int tid = threadIdx.x;
    int lane = tid & 63, wid = tid >> 6;
    int wr = wid / WGN, wc = wid % WGN;
    int fr = lane & 15, kq = lane >> 4;
    int r_in = lane >> 2, cg8 = (lane & 3) * 8;   // staging: 16 rows x 4 chunks

    f32x4 acc[MR][NR];
    #pragma unroll
    for (int i = 0; i < MR; ++i)
        #pragma unroll
        for (int j = 0; j < NR; ++j)
            acc[i][j] = (f32x4){0.f, 0.f, 0.f, 0.f};

    auto stage = [&](int buf, int kt) {
        #pragma unroll
        for (int t = 0; t < PW; ++t) {
            int j = wid * PW + t;                  // wave-uniform
            if (j < MI) {
                int row = j * 16 + r_in;
                gload_lds16(A + (size_t)(row0 + row) * K + kt + cg8,
                            &As[buf][j * 512]);
            } else {
                int jb = j - MI;
                int row = jb * 16 + r_in;
                gload_lds16(Bt + (size_t)(col0 + row) * K + kt + cg8,
                            &Bs[buf][jb * 512]);
            }
        }
    };
    auto compute = [&](int buf) {
        bf16x8 af[MR], bfv[NR];
        #pragma unroll
        for (int i = 0; i < MR; ++i)
            af[i] = *(const bf16x8*)&As[buf][(wr * WM + i * 16 + fr) * 32 + kq * 8];
        #pragma unroll
        for (int j = 0; j < NR; ++j)
            bfv[j] = *(const bf16x8*)&Bs[buf][(wc * WN + j * 16 + fr) * 32 + kq * 8];
        #pragma unroll
        for (int i = 0; i < MR; ++i)
            #pragma unroll
            for (int j = 0; j < NR; ++j)
                acc[i][j] = __builtin_amdgcn_mfma_f32_16x16x32_bf16(
                                af[i], bfv[j], acc[i][j], 0, 0, 0);
    };

    stage(0, 0);
    __syncthreads();                               // drains vmcnt -> buf0 ready
    int cur = 0;
    for (int kt = 32; kt < K; kt += 32) {
        stage(cur ^ 1, kt);                        // prefetch next (async)
        compute(cur);                              // overlap with loads
        __syncthreads();                           // drain + separate buffers
        cur ^= 1;
    }
    compute(cur);                                  // last tile, no prefetch

    int rg = kq * 4;
    #pragma unroll
    for (int j = 0; j < NR; ++j) {
        int col = col0 + wc * WN + j * 16 + fr;
        float bz = bias[col];
        #pragma unroll
        for (int i = 0; i < MR; ++i) {
            float v4[4];
            #pragma unroll
            for (int r = 0; r < 4; ++r) v4[r] = acc[i][j][r] + bz;
            if constexpr (FUSE_ROPE) {
                if (col0 < 2048) {                 // q,k cols: apply RoPE
                    int ii = (j * 16 + fr) >> 1;   // rotary pair idx (head-rel)
                    bool odd = fr & 1;
                    #pragma unroll
                    for (int r = 0; r < 4; ++r) {
                        float part = __shfl_xor(v4[r], 1);
                        int t = (row0 + wr * WM + i * 16 + rg + r) & 2047;
                        float c = tab[(t * 32 + ii) * 2];
                        float s = tab[(t * 32 + ii) * 2 + 1];
                        v4[r] = odd ? fmaf(v4[r], c,  part * s)
                                    : fmaf(v4[r], c, -part * s);
                    }
                }
            }
            #pragma unroll
            for (int r = 0; r < 4; ++r) {
                int row = row0 + wr * WM + i * 16 + rg + r;
                if constexpr (OUT_BF16)
                    ((unsigned short*)Cv)[(size_t)row * N + col] = f2bf(v4[r]);
                else
                    ((float*)Cv)[(size_t)row * N + col] = v4[r];
            }
        }
    }
}

// ---------------- RoPE table ------------------------------------------------
__global__ __launch_bounds__(256) void rope_table_kernel(float* __restrict__ tab) {
    int idx = blockIdx.x * 256 + threadIdx.x;   // 65536 = 2048*32
    int t = idx >> 5, i = idx & 31;
    float inv = powf(10000.0f, -(float)i / 32.0f);
    float ang = (float)t * inv;
    tab[idx * 2]     = cosf(ang);
    tab[idx * 2 + 1] = sinf(ang);
}

// ---------------- MFMA windowed causal attention ----------------------------
// Block = (b, h, 64-query tile), 4 waves, wave owns 16 queries.
#define VTS 200   // Vt col stride (keys): mult of 8 (16B align), 2-way banks
#define PSS 168   // P row stride: mult of 8, 2-way banks, >= 160

__global__ __launch_bounds__(256) void attn_kernel(
        const unsigned short* __restrict__ qkv, unsigned short* __restrict__ aout) {
    __shared__ unsigned short Vt[64 * VTS];        // 25600 B
    __shared__ unsigned short Ps[4 * 16 * PSS];    // 21504 B

    int bid = blockIdx.x;
    int h  = bid & 15;
    int qt = (bid >> 4) & 31;
    int b  = bid >> 9;
    int Q0 = qt * 64;
    int kbase = Q0 - 127; if (kbase < 0) kbase = 0;
    int nk = Q0 + 64 - kbase;                       // 64..191 valid keys
    int tid = threadIdx.x;

    // ---- stage V transposed: Vt[dim][key], zero keys in [nk, VTS) ----
    {
        int r32 = tid & 31;
        int c8  = (tid >> 5) * 8;
        #pragma unroll
        for (int p = 0; p < 7; ++p) {
            int r = p * 32 + r32;
            if (r < VTS) {
                unsigned int wv[4] = {0u, 0u, 0u, 0u};
                if (r < nk) {
                    uint4 v = *(const uint4*)(qkv +
                        (size_t)(b * 2048 + kbase + r) * 3072 + 2048 + h * 64 + c8);
                    wv[0] = v.x; wv[1] = v.y; wv[2] = v.z; wv[3] = v.w;
                }
                #pragma unroll
                for (int j = 0; j < 4; ++j) {
                    Vt[(c8 + 2 * j)     * VTS + r] = (unsigned short)(wv[j] & 0xffffu);
                    Vt[(c8 + 2 * j + 1) * VTS + r] = (unsigned short)(wv[j] >> 16);
                }
            }
        }
    }
    __syncthreads();

    int lane = tid & 63, w = tid >> 6;
    int qw0 = Q0 + w * 16;
    int lo = lane & 15, hi = lane >> 4;

    // ---- Q fragments (direct global) ----
    const unsigned short* qg =
        qkv + (size_t)(b * 2048 + qw0 + lo) * 3072 + h * 64 + hi * 8;
    bf16x8 aq0 = *(const bf16x8*)qg;
    bf16x8 aq1 = *(const bf16x8*)(qg + 32);

    // ---- key-tile range for this wave (even # of tiles when possible) ----
    int klo = qw0 - 127; if (klo < kbase) klo = kbase;
    int t0 = (klo - kbase) >> 4;
    int t1 = (qw0 + 15 - kbase) >> 4;
    int ntiles = t1 - t0 + 1;
    if ((ntiles & 1) && t0 > 0) { --t0; ++ntiles; }  // extra tile fully masked
    int nks = (ntiles + 1) >> 1;
    int wkb = t0 * 16;

    // ---- QK^T: S tiles (K frags direct from global) ----
    f32x4 s[10];
    #pragma unroll
    for (int i = 0; i < 10; ++i) s[i] = (f32x4){0.f, 0.f, 0.f, 0.f};
    #pragma unroll
    for (int i = 0; i < 10; ++i) {
        if (i < ntiles) {
            const unsigned short* kg = qkv +
                (size_t)(b * 2048 + kbase + (t0 + i) * 16 + lo) * 3072
                + 1024 + h * 64 + hi * 8;
            bf16x8 bk0 = *(const bf16x8*)kg;
            bf16x8 bk1 = *(const bf16x8*)(kg + 32);
            s[i] = __builtin_amdgcn_mfma_f32_16x16x32_bf16(aq0, bk0, s[i], 0, 0, 0);
            s[i] = __builtin_amdgcn_mfma_f32_16x16x32_bf16(aq1, bk1, s[i], 0, 0, 0);
        }
    }

    // ---- mask + softmax (rows = hi*4+r, cols = key) ----
    const float scale = 0.125f;                    // 1/sqrt(64)
    float mx[4] = {-1e30f, -1e30f, -1e30f, -1e30f};
    #pragma unroll
    for (int i = 0; i < 10; ++i) {
        if (i < ntiles) {
            int ka = kbase + (t0 + i) * 16 + lo;
            #pragma unroll
            for (int r = 0; r < 4; ++r) {
                int rel = (qw0 + hi * 4 + r) - ka;
                bool ok = (rel >= 0) && (rel < 128);
                float v = ok ? s[i][r] * scale : -1e30f;
                s[i][r] = v;
                mx[r] = fmaxf(mx[r], v);
            }
        }
    }
    #pragma unroll
    for (int r = 0; r < 4; ++r)
        #pragma unroll
        for (int o = 1; o < 16; o <<= 1)
            mx[r] = fmaxf(mx[r], __shfl_xor(mx[r], o));

    float sum[4] = {0.f, 0.f, 0.f, 0.f};
    #pragma unroll
    for (int i = 0; i < 10; ++i) {
        if (i < ntiles) {
            #pragma unroll
            for (int r = 0; r < 4; ++r) {
                float e = __expf(s[i][r] - mx[r]);
                s[i][r] = e;
                sum[r] += e;
            }
        }
    }
    #pragma unroll
    for (int r = 0; r < 4; ++r) {
        #pragma unroll
        for (int o = 1; o < 16; o <<= 1)
            sum[r] += __shfl_xor(sum[r], o);
        sum[r] = 1.0f / sum[r];
    }

    // ---- normalized P -> LDS (bf16) ----
    unsigned short* pw = &Ps[(w * 16) * PSS];
    #pragma unroll
    for (int i = 0; i < 10; ++i) {
        if (i < ntiles) {
            #pragma unroll
            for (int r = 0; r < 4; ++r)
                pw[(hi * 4 + r) * PSS + i * 16 + lo] = f2bf(s[i][r] * sum[r]);
        }
    }
    if (ntiles & 1) {                              // zero the pad stripe
        int zr = lane >> 2, zc = ntiles * 16 + (lane & 3) * 4;
        *(ushort4*)&pw[zr * PSS + zc] = (ushort4){0, 0, 0, 0};
    }

    // ---- PV: O[16q][64d] = P @ V ----
    f32x4 o[4];
    #pragma unroll
    for (int dt = 0; dt < 4; ++dt) o[dt] = (f32x4){0.f, 0.f, 0.f, 0.f};
    #pragma unroll
    for (int ks = 0; ks < 5; ++ks) {
        if (ks < nks) {
            bf16x8 pa = *(const bf16x8*)&Ps[(w * 16 + lo) * PSS + ks * 32 + hi * 8];
            #pragma unroll
            for (int dt = 0; dt < 4; ++dt) {
                bf16x8 vb = *(const bf16x8*)&Vt[(dt * 16 + lo) * VTS
                                                + wkb + ks * 32 + hi * 8];
                o[dt] = __builtin_amdgcn_mfma_f32_16x16x32_bf16(pa, vb, o[dt], 0, 0, 0);
            }
        }
    }

    // ---- store O (D-layout: col=dim=lo, row=hi*4+r) ----
    #pragma unroll
    for (int dt = 0; dt < 4; ++dt)
        #pragma unroll
        for (int r = 0; r < 4; ++r)
            aout[(size_t)(b * 2048 + qw0 + hi * 4 + r) * 1024
                 + h * 64 + dt * 16 + lo] = f2bf(o[dt][r]);
}

// ---------------------------------------------------------------------------
extern "C" void kernel_launch(void* const* d_in, const int* in_sizes, int n_in,
                              void* d_out, int out_size, void* d_ws, size_t ws_size,
                              hipStream_t stream) {
    const float* x     = (const float*)d_in[0];  // [2,2048,1024] fp32
    const float* Wqkv  = (const float*)d_in[1];  // [1024,3072]  fp32
    const float* bqkv  = (const float*)d_in[2];  // [3072]       fp32
    const float* Wproj = (const float*)d_in[3];  // [1024,1024]  fp32
    const float* bproj = (const float*)d_in[4];  // [1024]       fp32
    float* out = (float*)d_out;                  // [2,2048,1024] fp32

    char* ws = (char*)d_ws;
    unsigned short* WqkvT  = (unsigned short*)(ws);                // bf16 3072x1024:  6291456 B
    unsigned short* WprojT = (unsigned short*)(ws + 6291456);      // bf16 1024x1024:  2097152 B
    unsigned short* xb     = (unsigned short*)(ws + 8388608);      // bf16 4096x1024:  8388608 B
    unsigned short* qkv    = (unsigned short*)(ws + 16777216);     // bf16 4096x3072: 25165824 B
    float*          tab    = (float*)        (ws + 41943040);      // f32 2048x32x2:    524288 B
    unsigned short* attno  = (unsigned short*)(ws + 42467328);     // bf16 4096x1024:  8388608 B

    transpose_f32_bf16<<<dim3(96, 32), dim3(32, 8), 0, stream>>>(Wqkv,  WqkvT,  1024, 3072);
    transpose_f32_bf16<<<dim3(32, 32), dim3(32, 8), 0, stream>>>(Wproj, WprojT, 1024, 1024);
    f32_to_bf16_kernel<<<1024, 256, 0, stream>>>(x, xb, 4194304 / 4);
    rope_table_kernel<<<256, 256, 0, stream>>>(tab);

    // qkv = xb @ WqkvT^T + bqkv, RoPE fused in epilogue (bf16 out)
    gemm_lds<128, 128, 64, 64, true, true>
        <<<dim3(24, 32), 256, 0, stream>>>(xb, WqkvT, bqkv, qkv, tab, 4096, 3072, 1024);
    attn_kernel<<<1024, 256, 0, stream>>>(qkv, attno);
    // out = attno @ WprojT^T + bproj (fp32 out) 128x64 tile, 512 blocks
    gemm_lds<128, 64, 32, 64, false, false>
        <<<dim3(16, 32), 256, 0, stream>>>(attno, WprojT, bproj, out, nullptr, 4096, 1024, 1024);
}